// Round 1
// baseline (1238.415 us; speedup 1.0000x reference)
//
#include <hip/hip_runtime.h>
#include <hip/hip_bf16.h>

typedef __hip_bfloat16 bf16;
typedef __attribute__((ext_vector_type(4))) float f32x4;
typedef __attribute__((ext_vector_type(8))) short short8;

#define DEV __device__ __forceinline__
#define MFMA16(a, b, c) __builtin_amdgcn_mfma_f32_16x16x32_bf16(a, b, c, 0, 0, 0)

DEV void gload16(const void* g, void* l) {
  __builtin_amdgcn_global_load_lds((const __attribute__((address_space(1))) void*)g,
                                   (__attribute__((address_space(3))) void*)l, 16, 0, 0);
}

DEV unsigned short f2b(float f) {
  return __builtin_bit_cast(unsigned short, __float2bfloat16(f));
}

// ---------------------------------------------------------------------------
// Weight transpose + fp32->bf16 cast. src is (R x C) row-major fp32.
// dst[n][k] = src[k][c] with n = perm(c). permff applies the ff x/gate
// 16-block interleave so the fused-GEMM epilogue can gate without shuffles:
//   ff_x[p]    -> col 2304 + (p/16)*32 + p%16
//   ff_gate[p] -> col 2304 + (p/16)*32 + 16 + p%16
// ---------------------------------------------------------------------------
__global__ __launch_bounds__(256) void transpose_cast_kernel(
    const float* __restrict__ src, bf16* __restrict__ dst, int R, int C, int permff)
{
  __shared__ float tile[32][33];
  const int c0 = blockIdx.x * 32, k0 = blockIdx.y * 32;
  const int tx = threadIdx.x, ty = threadIdx.y;
#pragma unroll
  for (int r = 0; r < 4; ++r)
    tile[ty + 8 * r][tx] = src[(size_t)(k0 + ty + 8 * r) * C + c0 + tx];
  __syncthreads();
#pragma unroll
  for (int r = 0; r < 4; ++r) {
    int c = c0 + ty + 8 * r;
    int n = c;
    if (permff && c >= 2304) {
      int f = c - 2304;
      if (f < 8192) n = 2304 + ((f >> 4) << 5) + (f & 15);
      else { int f2 = f - 8192; n = 2304 + ((f2 >> 4) << 5) + 16 + (f2 & 15); }
    }
    dst[(size_t)n * R + k0 + tx] = __float2bfloat16(tile[tx][ty + 8 * r]);
  }
}

// ---------------------------------------------------------------------------
// LayerNorm: one block per row of 2048 fp32; writes bf16.
// ---------------------------------------------------------------------------
__global__ __launch_bounds__(256) void ln_kernel(
    const float* __restrict__ x, const float* __restrict__ gamma, bf16* __restrict__ o)
{
  const int row = blockIdx.x;
  const int t = threadIdx.x;
  const float4* xv = (const float4*)(x + (size_t)row * 2048) + t * 2;
  float4 a = xv[0], b = xv[1];
  float v[8] = {a.x, a.y, a.z, a.w, b.x, b.y, b.z, b.w};
  float s = 0.f, sq = 0.f;
#pragma unroll
  for (int i = 0; i < 8; ++i) { s += v[i]; sq += v[i] * v[i]; }
#pragma unroll
  for (int off = 32; off >= 1; off >>= 1) {
    s += __shfl_xor(s, off);
    sq += __shfl_xor(sq, off);
  }
  __shared__ float red[8];
  const int wave = t >> 6, lane = t & 63;
  if (lane == 0) { red[wave] = s; red[4 + wave] = sq; }
  __syncthreads();
  s = red[0] + red[1] + red[2] + red[3];
  sq = red[4] + red[5] + red[6] + red[7];
  const float mu = s * (1.f / 2048.f);
  const float var = sq * (1.f / 2048.f) - mu * mu;
  const float rs = rsqrtf(var + 1e-5f);
  const float4* gv = (const float4*)gamma + t * 2;
  float4 g0 = gv[0], g1 = gv[1];
  float gg[8] = {g0.x, g0.y, g0.z, g0.w, g1.x, g1.y, g1.z, g1.w};
  short8 pk;
#pragma unroll
  for (int i = 0; i < 8; ++i) pk[i] = f2b((v[i] - mu) * rs * gg[i]);
  *(short8*)(o + (size_t)row * 2048 + t * 8) = pk;
}

// ---------------------------------------------------------------------------
// GEMM C = A(MxK, row-major, lda) * B^T (B stored as N x K row-major bf16).
// m97 structure: 128x128 tile, 4 waves (2x2 of 64x64), BK=32, global_load_lds.
// MODE 0: fused split epilogue (q / k / v^T / gated-ff)   [GEMM1]
// MODE 1: store fp32 to out (stride 2048)                 [attn out]
// MODE 2: accumulate fp32 into out                        [ff out]
// ---------------------------------------------------------------------------
template <int MODE>
__global__ __launch_bounds__(256) void gemm_bt(
    const bf16* __restrict__ A, const bf16* __restrict__ B,
    int M, int N, int K, int lda,
    bf16* __restrict__ oq, bf16* __restrict__ okk, bf16* __restrict__ ovt,
    bf16* __restrict__ og, float* __restrict__ of)
{
  __shared__ bf16 As[128 * 32];
  __shared__ bf16 Bs[128 * 32];
  const int t = threadIdx.x;
  const int lane = t & 63;
  const int wave = t >> 6;
  const int wm = wave >> 1, wn = wave & 1;
  const int il = lane & 15, kg = lane >> 4;
  const int tm = blockIdx.x, tn = blockIdx.y;

  const int r0 = t >> 2, c0 = (t & 3) * 8;
  const bf16* ap0 = A + (size_t)(tm * 128 + r0) * lda + c0;
  const bf16* ap1 = A + (size_t)(tm * 128 + 64 + r0) * lda + c0;
  const bf16* bp0 = B + (size_t)(tn * 128 + r0) * K + c0;
  const bf16* bp1 = B + (size_t)(tn * 128 + 64 + r0) * K + c0;
  bf16* la0 = As + t * 8;
  bf16* la1 = As + (t + 256) * 8;
  bf16* lb0 = Bs + t * 8;
  bf16* lb1 = Bs + (t + 256) * 8;

  f32x4 acc[4][4];
#pragma unroll
  for (int m = 0; m < 4; ++m)
#pragma unroll
    for (int n = 0; n < 4; ++n) acc[m][n] = (f32x4){0.f, 0.f, 0.f, 0.f};

  for (int k0 = 0; k0 < K; k0 += 32) {
    gload16(ap0 + k0, la0);
    gload16(ap1 + k0, la1);
    gload16(bp0 + k0, lb0);
    gload16(bp1 + k0, lb1);
    __syncthreads();
    short8 af[4], bfg[4];
#pragma unroll
    for (int m = 0; m < 4; ++m)
      af[m] = *(const short8*)(As + (wm * 64 + m * 16 + il) * 32 + kg * 8);
#pragma unroll
    for (int n = 0; n < 4; ++n)
      bfg[n] = *(const short8*)(Bs + (wn * 64 + n * 16 + il) * 32 + kg * 8);
#pragma unroll
    for (int m = 0; m < 4; ++m)
#pragma unroll
      for (int n = 0; n < 4; ++n) acc[m][n] = MFMA16(af[m], bfg[n], acc[m][n]);
    __syncthreads();
  }

  const int n0 = tn * 128;
  const int rbase = tm * 128 + wm * 64;
  const int cbase = n0 + wn * 64;

  if constexpr (MODE == 0) {
    if (n0 < 2048) {                       // q (pre-RoPE), (b,n,2048) bf16
#pragma unroll
      for (int m = 0; m < 4; ++m)
#pragma unroll
        for (int n = 0; n < 4; ++n)
#pragma unroll
          for (int r = 0; r < 4; ++r)
            oq[(size_t)(rbase + m * 16 + kg * 4 + r) * 2048 + cbase + n * 16 + il] =
                __float2bfloat16(acc[m][n][r]);
    } else if (n0 < 2176) {                // k (pre-RoPE), (b,n,128) bf16
#pragma unroll
      for (int m = 0; m < 4; ++m)
#pragma unroll
        for (int n = 0; n < 4; ++n)
#pragma unroll
          for (int r = 0; r < 4; ++r)
            okk[(size_t)(rbase + m * 16 + kg * 4 + r) * 128 + (cbase - 2048 + n * 16 + il)] =
                __float2bfloat16(acc[m][n][r]);
    } else if (n0 < 2304) {                // v transposed: (b,128,2048) bf16
#pragma unroll
      for (int m = 0; m < 4; ++m)
#pragma unroll
        for (int n = 0; n < 4; ++n)
#pragma unroll
          for (int r = 0; r < 4; ++r) {
            int R = rbase + m * 16 + kg * 4 + r;
            int d = cbase - 2176 + n * 16 + il;
            ovt[(size_t)(R >> 11) * (128 * 2048) + (size_t)d * 2048 + (R & 2047)] =
                __float2bfloat16(acc[m][n][r]);
          }
    } else {                               // ff: fused SiLU gating, (4096,8192) bf16
#pragma unroll
      for (int m = 0; m < 4; ++m)
#pragma unroll
        for (int n = 0; n < 4; n += 2) {
          int p0 = ((n0 - 2304) >> 1) + (((wn * 4 + n) >> 1) << 4) + il;
#pragma unroll
          for (int r = 0; r < 4; ++r) {
            float xv = acc[m][n][r];
            float gvv = acc[m][n + 1][r];
            float ga = xv * gvv / (1.f + __expf(-gvv));
            og[(size_t)(rbase + m * 16 + kg * 4 + r) * 8192 + p0] = __float2bfloat16(ga);
          }
        }
    }
  } else {
#pragma unroll
    for (int m = 0; m < 4; ++m)
#pragma unroll
      for (int n = 0; n < 4; ++n)
#pragma unroll
        for (int r = 0; r < 4; ++r) {
          size_t idx = (size_t)(rbase + m * 16 + kg * 4 + r) * 2048 + cbase + n * 16 + il;
          if constexpr (MODE == 1) of[idx] = acc[m][n][r];
          else of[idx] += acc[m][n][r];
        }
  }
}

// ---------------------------------------------------------------------------
// RoPE in place. q: (b,n,16,128) bf16, also applies 1/sqrt(128).
// k: (b,n,128) bf16. Pair (d, d+64), angle = i * 10000^(-d/64).
// ---------------------------------------------------------------------------
__global__ __launch_bounds__(256) void rope_q_kernel(bf16* __restrict__ q)
{
  const int idx = blockIdx.x * 256 + threadIdx.x;   // 2^22 threads
  const int d = idx & 63;
  const int h = (idx >> 6) & 15;
  const int i = (idx >> 10) & 2047;
  const int b = idx >> 21;
  const size_t base = ((size_t)(b * 2048 + i)) * 2048 + h * 128 + d;
  const float x1 = __bfloat162float(q[base]);
  const float x2 = __bfloat162float(q[base + 64]);
  const double inv = exp2(-0.20762050593045972 * (double)d);   // log2(1e4)/64
  const float ang = (float)((double)i * inv);
  const float sn = sinf(ang), cs = cosf(ang);
  const float sc = 0.08838834764831845f;
  q[base] = __float2bfloat16((x1 * cs - x2 * sn) * sc);
  q[base + 64] = __float2bfloat16((x2 * cs + x1 * sn) * sc);
}

__global__ __launch_bounds__(256) void rope_k_kernel(bf16* __restrict__ k)
{
  const int idx = blockIdx.x * 256 + threadIdx.x;   // 2^18 threads
  const int d = idx & 63;
  const int i = (idx >> 6) & 2047;
  const int b = idx >> 17;
  const size_t base = ((size_t)(b * 2048 + i)) * 128 + d;
  const float x1 = __bfloat162float(k[base]);
  const float x2 = __bfloat162float(k[base + 64]);
  const double inv = exp2(-0.20762050593045972 * (double)d);
  const float ang = (float)((double)i * inv);
  const float sn = sinf(ang), cs = cosf(ang);
  k[base] = __float2bfloat16(x1 * cs - x2 * sn);
  k[base + 64] = __float2bfloat16(x2 * cs + x1 * sn);
}

// ---------------------------------------------------------------------------
// MQA flash attention. Grid (n/64, b*16). 4 waves, 16 q-rows per wave.
// S^T = K * Q^T so every lane owns ONE query column (i = lane&15):
// softmax reduce = 2x shfl_xor(16/32), O^T rescale is per-lane.
// K tile LDS-staged with XOR chunk swizzle (pre-swizzled global source).
// V read direct from global in transposed layout (L2-resident).
// Output written in place over q (block-exclusive region).
// ---------------------------------------------------------------------------
__global__ __launch_bounds__(256) void attn_kernel(
    const bf16* __restrict__ q, const bf16* __restrict__ kb, const bf16* __restrict__ vt,
    bf16* __restrict__ out, const int* __restrict__ vl)
{
  __shared__ __align__(16) unsigned char smem[51200];
  bf16* Ks = (bf16*)smem;                               // 128x128 bf16, swizzled
  const int t = threadIdx.x, lane = t & 63, wave = t >> 6;
  const int il = lane & 15, kg = lane >> 4;
  const int bh = blockIdx.y, b = bh >> 4, h = bh & 15;
  const int i0 = blockIdx.x * 64;
  const int vlb = vl[b];
  bf16* Plw = (bf16*)(smem + 32768 + wave * 4608);      // 16 x 144 bf16 per wave

  const int qrow = b * 2048 + i0 + wave * 16 + il;
  const bf16* qp = q + (size_t)qrow * 2048 + h * 128 + kg * 8;
  short8 qf[4];
#pragma unroll
  for (int kd = 0; kd < 4; ++kd) qf[kd] = *(const short8*)(qp + kd * 32);

  const bf16* vtb = vt + (size_t)b * (128 * 2048);

  f32x4 ot[8];
#pragma unroll
  for (int i = 0; i < 8; ++i) ot[i] = (f32x4){0.f, 0.f, 0.f, 0.f};
  float mrun = -1e30f, lrun = 0.f;

  const int ntile = (vlb + 127) >> 7;
  for (int tt = 0; tt < ntile; ++tt) {
    const int j0 = tt << 7;
    // stage K tile (pre-swizzled source so linear LDS = swizzled layout)
#pragma unroll
    for (int u = 0; u < 8; ++u) {
      int id = u * 256 + t;
      int row = id >> 4, cc = id & 15;
      int csw = cc ^ (row & 7);
      gload16(kb + (size_t)(b * 2048 + j0 + row) * 128 + csw * 8, Ks + id * 8);
    }
    __syncthreads();
    // S^T = K * Q^T
    f32x4 st[8];
#pragma unroll
    for (int jb = 0; jb < 8; ++jb) {
      f32x4 a = (f32x4){0.f, 0.f, 0.f, 0.f};
      const int row = jb * 16 + il;
      const int rx = row & 7;
#pragma unroll
      for (int kd = 0; kd < 4; ++kd) {
        int slot = (kd * 4 + kg) ^ rx;
        short8 kf = *(const short8*)(Ks + row * 128 + slot * 8);
        a = MFMA16(kf, qf[kd], a);
      }
      st[jb] = a;
    }
    // vl mask (last tile only)
    if (j0 + 128 > vlb) {
#pragma unroll
      for (int jb = 0; jb < 8; ++jb)
#pragma unroll
        for (int r = 0; r < 4; ++r)
          if (j0 + jb * 16 + kg * 4 + r >= vlb) st[jb][r] = -1e30f;
    }
    // online softmax (each lane: one query i, 32 j values)
    float tmax = -1e30f;
#pragma unroll
    for (int jb = 0; jb < 8; ++jb)
#pragma unroll
      for (int r = 0; r < 4; ++r) tmax = fmaxf(tmax, st[jb][r]);
    tmax = fmaxf(tmax, __shfl_xor(tmax, 16));
    tmax = fmaxf(tmax, __shfl_xor(tmax, 32));
    const float mnew = fmaxf(mrun, tmax);
    const float scale = __expf(mrun - mnew);
    float ls = 0.f;
#pragma unroll
    for (int jb = 0; jb < 8; ++jb)
#pragma unroll
      for (int r = 0; r < 4; ++r) {
        float p = __expf(st[jb][r] - mnew);
        st[jb][r] = p;
        ls += p;
      }
    ls += __shfl_xor(ls, 16);
    ls += __shfl_xor(ls, 32);
    lrun = lrun * scale + ls;
    mrun = mnew;
#pragma unroll
    for (int db = 0; db < 8; ++db) ot[db] *= scale;
    // P^T -> LDS (row i = lane&15, col j)
#pragma unroll
    for (int jb = 0; jb < 8; ++jb)
#pragma unroll
      for (int r = 0; r < 4; ++r)
        Plw[il * 144 + jb * 16 + kg * 4 + r] = __float2bfloat16(st[jb][r]);
    // O^T += V^T * P^T   (V^T direct from global, contiguous 16B)
#pragma unroll
    for (int db = 0; db < 8; ++db) {
      const bf16* vp = vtb + (size_t)(db * 16 + il) * 2048 + j0 + kg * 8;
      f32x4 o = ot[db];
#pragma unroll
      for (int kj = 0; kj < 4; ++kj) {
        short8 vf = *(const short8*)(vp + kj * 32);
        short8 pf = *(const short8*)(Plw + il * 144 + kj * 32 + kg * 8);
        o = MFMA16(vf, pf, o);
      }
      ot[db] = o;
    }
    __syncthreads();   // all waves done with Ks before next stage / smem reuse
  }

  const float inv = 1.f / lrun;
#pragma unroll
  for (int db = 0; db < 8; ++db) ot[db] *= inv;

  // transpose O^T -> O via LDS (padded 132), then coalesced bf16 store over q
  float* Osw = (float*)smem + wave * 2112;   // 16 x 132 fp32 per wave
#pragma unroll
  for (int db = 0; db < 8; ++db)
#pragma unroll
    for (int r = 0; r < 4; ++r)
      Osw[il * 132 + db * 16 + kg * 4 + r] = ot[db][r];
  __builtin_amdgcn_s_waitcnt(0);  // lgkm drain handled by compiler deps; keep simple
  const int orow = lane >> 2;     // 0..15
  const int seg = lane & 3;       // 0..3 (32 d each)
  const size_t obase = (size_t)(b * 2048 + i0 + wave * 16 + orow) * 2048 + h * 128 + seg * 32;
#pragma unroll
  for (int u = 0; u < 4; ++u) {
    short8 pk;
#pragma unroll
    for (int e = 0; e < 8; ++e) pk[e] = f2b(Osw[orow * 132 + seg * 32 + u * 8 + e]);
    *(short8*)(out + obase + u * 8) = pk;
  }
}

// ---------------------------------------------------------------------------
extern "C" void kernel_launch(void* const* d_in, const int* in_sizes, int n_in,
                              void* d_out, int out_size, void* d_ws, size_t ws_size,
                              hipStream_t stream)
{
  const float* x       = (const float*)d_in[0];
  const int*   vl      = (const int*)d_in[1];
  const float* gamma   = (const float*)d_in[2];
  const float* w_fused = (const float*)d_in[3];
  const float* w_attn  = (const float*)d_in[4];
  const float* w_ff    = (const float*)d_in[5];
  float* out = (float*)d_out;
  char* ws = (char*)d_ws;

  bf16* wfT  = (bf16*)(ws);                  // 18688 x 2048   (76,546,048 B)
  bf16* waoT = (bf16*)(ws + 76546048);       // 2048 x 2048    ( 8,388,608 B)
  bf16* wffT = (bf16*)(ws + 84934656);       // 2048 x 8192    (33,554,432 B)
  bf16* xn   = (bf16*)(ws + 118489088);      // 4096 x 2048    (16,777,216 B)
  bf16* qb   = (bf16*)(ws + 135266304);      // 4096 x 2048    (16,777,216 B)
  bf16* kb   = (bf16*)(ws + 152043520);      // 2 x 2048 x 128 ( 1,048,576 B)
  bf16* vtb  = (bf16*)(ws + 153092096);      // 2 x 128 x 2048 ( 1,048,576 B)
  bf16* gb   = (bf16*)(ws + 154140672);      // 4096 x 8192    (67,108,864 B)
  // total 221,249,536 B

  transpose_cast_kernel<<<dim3(584, 64), dim3(32, 8), 0, stream>>>(w_fused, wfT, 2048, 18688, 1);
  transpose_cast_kernel<<<dim3(64, 64), dim3(32, 8), 0, stream>>>(w_attn, waoT, 2048, 2048, 0);
  transpose_cast_kernel<<<dim3(64, 256), dim3(32, 8), 0, stream>>>(w_ff, wffT, 8192, 2048, 0);
  ln_kernel<<<4096, 256, 0, stream>>>(x, gamma, xn);
  gemm_bt<0><<<dim3(32, 146), 256, 0, stream>>>(xn, wfT, 4096, 18688, 2048, 2048,
                                                qb, kb, vtb, gb, nullptr);
  rope_q_kernel<<<16384, 256, 0, stream>>>(qb);
  rope_k_kernel<<<1024, 256, 0, stream>>>(kb);
  attn_kernel<<<dim3(32, 32), 256, 0, stream>>>(qb, kb, vtb, qb, vl);
  gemm_bt<1><<<dim3(32, 16), 256, 0, stream>>>(qb, waoT, 4096, 2048, 2048, 2048,
                                               nullptr, nullptr, nullptr, nullptr, out);
  gemm_bt<2><<<dim3(32, 16), 256, 0, stream>>>(gb, wffT, 4096, 2048, 8192, 8192,
                                               nullptr, nullptr, nullptr, nullptr, out);
}

// Round 3
// 1069.700 us; speedup vs baseline: 1.1577x; 1.1577x over previous
//
#include <hip/hip_runtime.h>
#include <hip/hip_bf16.h>

typedef __hip_bfloat16 bf16;
typedef __attribute__((ext_vector_type(4))) float f32x4;
typedef __attribute__((ext_vector_type(8))) short short8;

#define DEV __device__ __forceinline__
#define MFMA16(a, b, c) __builtin_amdgcn_mfma_f32_16x16x32_bf16(a, b, c, 0, 0, 0)

DEV void gload16(const void* g, void* l) {
  __builtin_amdgcn_global_load_lds((const __attribute__((address_space(1))) void*)g,
                                   (__attribute__((address_space(3))) void*)l, 16, 0, 0);
}

DEV unsigned short f2b(float f) {
  return __builtin_bit_cast(unsigned short, __float2bfloat16(f));
}

#define S_BARRIER() asm volatile("s_barrier" ::: "memory")
#define LGKM0()                                              \
  do {                                                       \
    asm volatile("s_waitcnt lgkmcnt(0)" ::: "memory");       \
    __builtin_amdgcn_sched_barrier(0);                       \
  } while (0)

// ---------------------------------------------------------------------------
// Weight transpose + fp32->bf16 cast. src is (R x C) row-major fp32.
// dst[n][k] = src[k][c] with n = perm(c). permff applies the ff x/gate
// 16-block interleave so the fused-GEMM epilogue can gate without shuffles.
// ---------------------------------------------------------------------------
__global__ __launch_bounds__(256) void transpose_cast_kernel(
    const float* __restrict__ src, bf16* __restrict__ dst, int R, int C, int permff)
{
  __shared__ float tile[32][33];
  const int c0 = blockIdx.x * 32, k0 = blockIdx.y * 32;
  const int tx = threadIdx.x, ty = threadIdx.y;
#pragma unroll
  for (int r = 0; r < 4; ++r)
    tile[ty + 8 * r][tx] = src[(size_t)(k0 + ty + 8 * r) * C + c0 + tx];
  __syncthreads();
#pragma unroll
  for (int r = 0; r < 4; ++r) {
    int c = c0 + ty + 8 * r;
    int n = c;
    if (permff && c >= 2304) {
      int f = c - 2304;
      if (f < 8192) n = 2304 + ((f >> 4) << 5) + (f & 15);
      else { int f2 = f - 8192; n = 2304 + ((f2 >> 4) << 5) + 16 + (f2 & 15); }
    }
    dst[(size_t)n * R + k0 + tx] = __float2bfloat16(tile[tx][ty + 8 * r]);
  }
}

// ---------------------------------------------------------------------------
// LayerNorm: one block per row of 2048 fp32; writes bf16.
// ---------------------------------------------------------------------------
__global__ __launch_bounds__(256) void ln_kernel(
    const float* __restrict__ x, const float* __restrict__ gamma, bf16* __restrict__ o)
{
  const int row = blockIdx.x;
  const int t = threadIdx.x;
  const float4* xv = (const float4*)(x + (size_t)row * 2048) + t * 2;
  float4 a = xv[0], b = xv[1];
  float v[8] = {a.x, a.y, a.z, a.w, b.x, b.y, b.z, b.w};
  float s = 0.f, sq = 0.f;
#pragma unroll
  for (int i = 0; i < 8; ++i) { s += v[i]; sq += v[i] * v[i]; }
#pragma unroll
  for (int off = 32; off >= 1; off >>= 1) {
    s += __shfl_xor(s, off);
    sq += __shfl_xor(sq, off);
  }
  __shared__ float red[8];
  const int wave = t >> 6, lane = t & 63;
  if (lane == 0) { red[wave] = s; red[4 + wave] = sq; }
  __syncthreads();
  s = red[0] + red[1] + red[2] + red[3];
  sq = red[4] + red[5] + red[6] + red[7];
  const float mu = s * (1.f / 2048.f);
  const float var = sq * (1.f / 2048.f) - mu * mu;
  const float rs = rsqrtf(var + 1e-5f);
  const float4* gv = (const float4*)gamma + t * 2;
  float4 g0 = gv[0], g1 = gv[1];
  float gg[8] = {g0.x, g0.y, g0.z, g0.w, g1.x, g1.y, g1.z, g1.w};
  short8 pk;
#pragma unroll
  for (int i = 0; i < 8; ++i) pk[i] = f2b((v[i] - mu) * rs * gg[i]);
  *(short8*)(o + (size_t)row * 2048 + t * 8) = pk;
}

// ---------------------------------------------------------------------------
// 8-phase 256-wide GEMM  C = A(MxK, stride K) * B^T (B stored N x K bf16).
// BM=256, BK=64, 8 waves. WN=4: BN=256 (2x4 waves, 128x64/wave, acc[8][4]).
//                         WN=2: BN=128 (4x2 waves,  64x64/wave, acc[4][4]).
// st_16x32 LDS swizzle (pre-swizzled global source, linear global_load_lds
// dest), counted vmcnt (never 0 in steady state), raw s_barrier, setprio
// around MFMA clusters, XCD-bijective block swizzle.
// MODE 0: fused split epilogue (q / k / v^T / gated-ff)   [WN=4 only]
// MODE 1: store fp32 to out (stride 2048)
// MODE 2: accumulate fp32 into out
// ---------------------------------------------------------------------------
template <int MODE, int WN>
__global__ __launch_bounds__(512, 2) void gemm8p(
    const bf16* __restrict__ A, const bf16* __restrict__ Bw,
    int Kd, int NT_M,
    bf16* __restrict__ oq, bf16* __restrict__ okk, bf16* __restrict__ ovt,
    bf16* __restrict__ og, float* __restrict__ of)
{
  constexpr int MR = (WN == 4) ? 8 : 4;      // m-fragments per wave
  constexpr int BN = WN * 64;
  constexpr int ABYTES = 32768;              // 256 x 64 bf16
  constexpr int BBYTES = BN * 64 * 2;
  constexpr int BUFB = ABYTES + BBYTES;
  constexpr int VW = 2 + (WN >> 1);          // per-wave loads per kh-group
  __shared__ __align__(16) char ldsb[2 * BUFB];

  const int t = threadIdx.x;
  const int lane = t & 63, wid = t >> 6;
  const int il = lane & 15, kg = lane >> 4;
  const int wn = wid % WN, wm = wid / WN;

  const int nwg = gridDim.x;
  const int bid = blockIdx.x;
  const int v = (bid & 7) * (nwg >> 3) + (bid >> 3);   // XCD swizzle (nwg%8==0)
  const int tm = v % NT_M, tn = v / NT_M;

  // staging lane geometry: lane l writes LDS bytes [l*16, l*16+16) of a
  // 1024B subtile; inverse st_16x32 swizzle gives the (row, col) to fetch.
  const int l16 = lane * 16;
  const int w0 = l16 ^ (((l16 >> 9) & 1) << 5);
  const int r_in = w0 >> 6;          // 0..15
  const int c_in = (w0 & 63) >> 1;   // 0,8,16,24 (bf16 elems)

  // fragment-read byte offset inside a swizzled subtile
  const int swz = (il * 64 + kg * 16) ^ ((il >> 3) << 5);

  const bf16* Abase = A + (size_t)(tm * 256) * Kd;
  const bf16* Bbase = Bw + (size_t)(tn * BN) * Kd;
  const size_t laneOff = (size_t)r_in * Kd + c_in;

  const int NT = Kd >> 6;

  f32x4 acc[MR][4];
#pragma unroll
  for (int m = 0; m < MR; ++m)
#pragma unroll
    for (int n = 0; n < 4; ++n) acc[m][n] = (f32x4){0.f, 0.f, 0.f, 0.f};

  auto stageA = [&](int b, int k0, int kh) {
#pragma unroll
    for (int s = 0; s < 2; ++s) {
      const int sr = wid * 2 + s;                       // 0..15
      gload16(Abase + (size_t)(sr * 16) * Kd + (k0 + kh * 32) + laneOff,
              ldsb + b * BUFB + (sr * 2 + kh) * 1024 + l16);
    }
  };
  auto stageB = [&](int b, int k0, int kh) {
    if constexpr (WN == 4) {
#pragma unroll
      for (int s = 0; s < 2; ++s) {
        const int sr = wid * 2 + s;
        gload16(Bbase + (size_t)(sr * 16) * Kd + (k0 + kh * 32) + laneOff,
                ldsb + b * BUFB + ABYTES + (sr * 2 + kh) * 1024 + l16);
      }
    } else {
      const int sr = wid;                               // 0..7
      gload16(Bbase + (size_t)(sr * 16) * Kd + (k0 + kh * 32) + laneOff,
              ldsb + b * BUFB + ABYTES + (sr * 2 + kh) * 1024 + l16);
    }
  };
  auto rdA = [&](int b, int m, int ks) -> short8 {
    return *(const short8*)(ldsb + b * BUFB + (wm * MR + m) * 2048 + ks * 1024 + swz);
  };
  auto rdB = [&](int b, int n, int ks) -> short8 {
    return *(const short8*)(ldsb + b * BUFB + ABYTES + (wn * 4 + n) * 2048 + ks * 1024 + swz);
  };

  // prologue: stage tile 0 (kh0 group then kh1 group), drain kh0, barrier
  stageA(0, 0, 0);
  stageB(0, 0, 0);
  stageA(0, 0, 1);
  stageB(0, 0, 1);
  asm volatile("s_waitcnt vmcnt(%0)" ::"n"(VW) : "memory");
  S_BARRIER();

  short8 a0[MR], a1[MR], b0[4], b1[4];

  for (int jt = 0; jt < NT; ++jt) {
    const int b = jt & 1, nb = b ^ 1;
    const int k1 = (jt + 1) << 6;
    const bool hn = (jt + 1) < NT;

    // ---- phase 1: A(ks0) + B01(ks0); stage A-kh0(next); MFMA n0,n1 x ks0
#pragma unroll
    for (int m = 0; m < MR; ++m) a0[m] = rdA(b, m, 0);
    b0[0] = rdB(b, 0, 0);
    b0[1] = rdB(b, 1, 0);
    if (hn) stageA(nb, k1, 0);
    S_BARRIER();
    LGKM0();
    __builtin_amdgcn_s_setprio(1);
#pragma unroll
    for (int m = 0; m < MR; ++m) {
      acc[m][0] = MFMA16(a0[m], b0[0], acc[m][0]);
      acc[m][1] = MFMA16(a0[m], b0[1], acc[m][1]);
    }
    __builtin_amdgcn_s_setprio(0);
    S_BARRIER();

    // ---- phase 2: B23(ks0); stage B-kh0(next); MFMA n2,n3 x ks0; vmcnt
    b0[2] = rdB(b, 2, 0);
    b0[3] = rdB(b, 3, 0);
    if (hn) stageB(nb, k1, 0);
    S_BARRIER();
    LGKM0();
    __builtin_amdgcn_s_setprio(1);
#pragma unroll
    for (int m = 0; m < MR; ++m) {
      acc[m][2] = MFMA16(a0[m], b0[2], acc[m][2]);
      acc[m][3] = MFMA16(a0[m], b0[3], acc[m][3]);
    }
    __builtin_amdgcn_s_setprio(0);
    if (hn) { asm volatile("s_waitcnt vmcnt(%0)" ::"n"(VW) : "memory"); }
    else    { asm volatile("s_waitcnt vmcnt(0)" ::: "memory"); }
    S_BARRIER();

    // ---- phase 3: A(ks1) + B01(ks1); stage A-kh1(next); MFMA n0,n1 x ks1
#pragma unroll
    for (int m = 0; m < MR; ++m) a1[m] = rdA(b, m, 1);
    b1[0] = rdB(b, 0, 1);
    b1[1] = rdB(b, 1, 1);
    if (hn) stageA(nb, k1, 1);
    S_BARRIER();
    LGKM0();
    __builtin_amdgcn_s_setprio(1);
#pragma unroll
    for (int m = 0; m < MR; ++m) {
      acc[m][0] = MFMA16(a1[m], b1[0], acc[m][0]);
      acc[m][1] = MFMA16(a1[m], b1[1], acc[m][1]);
    }
    __builtin_amdgcn_s_setprio(0);
    S_BARRIER();

    // ---- phase 4: B23(ks1); stage B-kh1(next); MFMA n2,n3 x ks1; vmcnt
    b1[2] = rdB(b, 2, 1);
    b1[3] = rdB(b, 3, 1);
    if (hn) stageB(nb, k1, 1);
    S_BARRIER();
    LGKM0();
    __builtin_amdgcn_s_setprio(1);
#pragma unroll
    for (int m = 0; m < MR; ++m) {
      acc[m][2] = MFMA16(a1[m], b1[2], acc[m][2]);
      acc[m][3] = MFMA16(a1[m], b1[3], acc[m][3]);
    }
    __builtin_amdgcn_s_setprio(0);
    if (hn) { asm volatile("s_waitcnt vmcnt(%0)" ::"n"(VW) : "memory"); }
    S_BARRIER();
  }

  // ---------------- epilogue ----------------
  const int rb = tm * 256 + wm * (WN * 32);   // rows-per-wave: WN4->128, WN2->64
  const int cb = tn * BN + wn * 64;

  if constexpr (MODE == 0) {
    if (cb < 2048) {                       // q (pre-RoPE), (b,n,2048) bf16
#pragma unroll
      for (int m = 0; m < MR; ++m)
#pragma unroll
        for (int n = 0; n < 4; ++n)
#pragma unroll
          for (int r = 0; r < 4; ++r)
            oq[(size_t)(rb + m * 16 + kg * 4 + r) * 2048 + cb + n * 16 + il] =
                __float2bfloat16(acc[m][n][r]);
    } else if (cb < 2176) {                // k (pre-RoPE), (b,n,128) bf16
#pragma unroll
      for (int m = 0; m < MR; ++m)
#pragma unroll
        for (int n = 0; n < 4; ++n)
#pragma unroll
          for (int r = 0; r < 4; ++r)
            okk[(size_t)(rb + m * 16 + kg * 4 + r) * 128 + (cb - 2048 + n * 16 + il)] =
                __float2bfloat16(acc[m][n][r]);
    } else if (cb < 2304) {                // v transposed: (b,128,2048) bf16
#pragma unroll
      for (int m = 0; m < MR; ++m)
#pragma unroll
        for (int n = 0; n < 4; ++n)
#pragma unroll
          for (int r = 0; r < 4; ++r) {
            int R = rb + m * 16 + kg * 4 + r;
            int d = cb - 2176 + n * 16 + il;
            ovt[(size_t)(R >> 11) * (128 * 2048) + (size_t)d * 2048 + (R & 2047)] =
                __float2bfloat16(acc[m][n][r]);
          }
    } else {                               // ff: fused SiLU gating, (4096,8192) bf16
#pragma unroll
      for (int m = 0; m < MR; ++m)
#pragma unroll
        for (int n = 0; n < 4; n += 2) {
          int p0 = ((cb + n * 16 - 2304) >> 5) * 16 + il;
#pragma unroll
          for (int r = 0; r < 4; ++r) {
            float xv = acc[m][n][r];
            float gvv = acc[m][n + 1][r];
            float ga = xv * gvv / (1.f + __expf(-gvv));
            og[(size_t)(rb + m * 16 + kg * 4 + r) * 8192 + p0] = __float2bfloat16(ga);
          }
        }
    }
  } else {
#pragma unroll
    for (int m = 0; m < MR; ++m)
#pragma unroll
      for (int n = 0; n < 4; ++n)
#pragma unroll
        for (int r = 0; r < 4; ++r) {
          size_t idx = (size_t)(rb + m * 16 + kg * 4 + r) * 2048 + cb + n * 16 + il;
          if constexpr (MODE == 1) of[idx] = acc[m][n][r];
          else of[idx] += acc[m][n][r];
        }
  }
}

// ---------------------------------------------------------------------------
// RoPE in place. q: (b,n,16,128) bf16, also applies 1/sqrt(128).
// k: (b,n,128) bf16. Pair (d, d+64), angle = i * 10000^(-d/64).
// ---------------------------------------------------------------------------
__global__ __launch_bounds__(256) void rope_q_kernel(bf16* __restrict__ q)
{
  const int idx = blockIdx.x * 256 + threadIdx.x;   // 2^22 threads
  const int d = idx & 63;
  const int h = (idx >> 6) & 15;
  const int i = (idx >> 10) & 2047;
  const int b = idx >> 21;
  const size_t base = ((size_t)(b * 2048 + i)) * 2048 + h * 128 + d;
  const float x1 = __bfloat162float(q[base]);
  const float x2 = __bfloat162float(q[base + 64]);
  const double inv = exp2(-0.20762050593045972 * (double)d);   // log2(1e4)/64
  const float ang = (float)((double)i * inv);
  const float sn = sinf(ang), cs = cosf(ang);
  const float sc = 0.08838834764831845f;
  q[base] = __float2bfloat16((x1 * cs - x2 * sn) * sc);
  q[base + 64] = __float2bfloat16((x2 * cs + x1 * sn) * sc);
}

__global__ __launch_bounds__(256) void rope_k_kernel(bf16* __restrict__ k)
{
  const int idx = blockIdx.x * 256 + threadIdx.x;   // 2^18 threads
  const int d = idx & 63;
  const int i = (idx >> 6) & 2047;
  const int b = idx >> 17;
  const size_t base = ((size_t)(b * 2048 + i)) * 128 + d;
  const float x1 = __bfloat162float(k[base]);
  const float x2 = __bfloat162float(k[base + 64]);
  const double inv = exp2(-0.20762050593045972 * (double)d);
  const float ang = (float)((double)i * inv);
  const float sn = sinf(ang), cs = cosf(ang);
  k[base] = __float2bfloat16(x1 * cs - x2 * sn);
  k[base + 64] = __float2bfloat16(x2 * cs + x1 * sn);
}

// ---------------------------------------------------------------------------
// MQA flash attention. Grid (n/64, b*16). 4 waves, 16 q-rows per wave.
// S^T = K * Q^T so every lane owns ONE query column (i = lane&15):
// softmax reduce = 2x shfl_xor(16/32), O^T rescale is per-lane.
// K tile LDS-staged with XOR chunk swizzle (pre-swizzled global source).
// V read direct from global in transposed layout (L2-resident).
// Output written in place over q (block-exclusive region).
// ---------------------------------------------------------------------------
__global__ __launch_bounds__(256) void attn_kernel(
    const bf16* __restrict__ q, const bf16* __restrict__ kb, const bf16* __restrict__ vt,
    bf16* __restrict__ out, const int* __restrict__ vl)
{
  __shared__ __align__(16) unsigned char smem[51200];
  bf16* Ks = (bf16*)smem;                               // 128x128 bf16, swizzled
  const int t = threadIdx.x, lane = t & 63, wave = t >> 6;
  const int il = lane & 15, kg = lane >> 4;
  const int bh = blockIdx.y, b = bh >> 4, h = bh & 15;
  const int i0 = blockIdx.x * 64;
  const int vlb = vl[b];
  bf16* Plw = (bf16*)(smem + 32768 + wave * 4608);      // 16 x 144 bf16 per wave

  const int qrow = b * 2048 + i0 + wave * 16 + il;
  const bf16* qp = q + (size_t)qrow * 2048 + h * 128 + kg * 8;
  short8 qf[4];
#pragma unroll
  for (int kd = 0; kd < 4; ++kd) qf[kd] = *(const short8*)(qp + kd * 32);

  const bf16* vtb = vt + (size_t)b * (128 * 2048);

  f32x4 ot[8];
#pragma unroll
  for (int i = 0; i < 8; ++i) ot[i] = (f32x4){0.f, 0.f, 0.f, 0.f};
  float mrun = -1e30f, lrun = 0.f;

  const int ntile = (vlb + 127) >> 7;
  for (int tt = 0; tt < ntile; ++tt) {
    const int j0 = tt << 7;
    // stage K tile (pre-swizzled source so linear LDS = swizzled layout)
#pragma unroll
    for (int u = 0; u < 8; ++u) {
      int id = u * 256 + t;
      int row = id >> 4, cc = id & 15;
      int csw = cc ^ (row & 7);
      gload16(kb + (size_t)(b * 2048 + j0 + row) * 128 + csw * 8, Ks + id * 8);
    }
    __syncthreads();
    // S^T = K * Q^T
    f32x4 st[8];
#pragma unroll
    for (int jb = 0; jb < 8; ++jb) {
      f32x4 a = (f32x4){0.f, 0.f, 0.f, 0.f};
      const int row = jb * 16 + il;
      const int rx = row & 7;
#pragma unroll
      for (int kd = 0; kd < 4; ++kd) {
        int slot = (kd * 4 + kg) ^ rx;
        short8 kf = *(const short8*)(Ks + row * 128 + slot * 8);
        a = MFMA16(kf, qf[kd], a);
      }
      st[jb] = a;
    }
    // vl mask (last tile only)
    if (j0 + 128 > vlb) {
#pragma unroll
      for (int jb = 0; jb < 8; ++jb)
#pragma unroll
        for (int r = 0; r < 4; ++r)
          if (j0 + jb * 16 + kg * 4 + r >= vlb) st[jb][r] = -1e30f;
    }
    // online softmax (each lane: one query i, 32 j values)
    float tmax = -1e30f;
#pragma unroll
    for (int jb = 0; jb < 8; ++jb)
#pragma unroll
      for (int r = 0; r < 4; ++r) tmax = fmaxf(tmax, st[jb][r]);
    tmax = fmaxf(tmax, __shfl_xor(tmax, 16));
    tmax = fmaxf(tmax, __shfl_xor(tmax, 32));
    const float mnew = fmaxf(mrun, tmax);
    const float scale = __expf(mrun - mnew);
    float ls = 0.f;
#pragma unroll
    for (int jb = 0; jb < 8; ++jb)
#pragma unroll
      for (int r = 0; r < 4; ++r) {
        float p = __expf(st[jb][r] - mnew);
        st[jb][r] = p;
        ls += p;
      }
    ls += __shfl_xor(ls, 16);
    ls += __shfl_xor(ls, 32);
    lrun = lrun * scale + ls;
    mrun = mnew;
#pragma unroll
    for (int db = 0; db < 8; ++db) ot[db] *= scale;
    // P^T -> LDS (row i = lane&15, col j)
#pragma unroll
    for (int jb = 0; jb < 8; ++jb)
#pragma unroll
      for (int r = 0; r < 4; ++r)
        Plw[il * 144 + jb * 16 + kg * 4 + r] = __float2bfloat16(st[jb][r]);
    // O^T += V^T * P^T   (V^T direct from global, contiguous 16B)
#pragma unroll
    for (int db = 0; db < 8; ++db) {
      const bf16* vp = vtb + (size_t)(db * 16 + il) * 2048 + j0 + kg * 8;
      f32x4 o = ot[db];
#pragma unroll
      for (int kj = 0; kj < 4; ++kj) {
        short8 vf = *(const short8*)(vp + kj * 32);
        short8 pf = *(const short8*)(Plw + il * 144 + kj * 32 + kg * 8);
        o = MFMA16(vf, pf, o);
      }
      ot[db] = o;
    }
    __syncthreads();   // all waves done with Ks before next stage / smem reuse
  }

  const float inv = 1.f / lrun;
#pragma unroll
  for (int db = 0; db < 8; ++db) ot[db] *= inv;

  // transpose O^T -> O via LDS (padded 132), then coalesced bf16 store over q
  float* Osw = (float*)smem + wave * 2112;   // 16 x 132 fp32 per wave
#pragma unroll
  for (int db = 0; db < 8; ++db)
#pragma unroll
    for (int r = 0; r < 4; ++r)
      Osw[il * 132 + db * 16 + kg * 4 + r] = ot[db][r];
  const int orow = lane >> 2;     // 0..15
  const int seg = lane & 3;       // 0..3 (32 d each)
  const size_t obase = (size_t)(b * 2048 + i0 + wave * 16 + orow) * 2048 + h * 128 + seg * 32;
#pragma unroll
  for (int u = 0; u < 4; ++u) {
    short8 pk;
#pragma unroll
    for (int e = 0; e < 8; ++e) pk[e] = f2b(Osw[orow * 132 + seg * 32 + u * 8 + e]);
    *(short8*)(out + obase + u * 8) = pk;
  }
}

// ---------------------------------------------------------------------------
extern "C" void kernel_launch(void* const* d_in, const int* in_sizes, int n_in,
                              void* d_out, int out_size, void* d_ws, size_t ws_size,
                              hipStream_t stream)
{
  const float* x       = (const float*)d_in[0];
  const int*   vl      = (const int*)d_in[1];
  const float* gamma   = (const float*)d_in[2];
  const float* w_fused = (const float*)d_in[3];
  const float* w_attn  = (const float*)d_in[4];
  const float* w_ff    = (const float*)d_in[5];
  float* out = (float*)d_out;
  char* ws = (char*)d_ws;

  bf16* wfT  = (bf16*)(ws);                  // 18688 x 2048   (76,546,048 B)
  bf16* waoT = (bf16*)(ws + 76546048);       // 2048 x 2048    ( 8,388,608 B)
  bf16* wffT = (bf16*)(ws + 84934656);       // 2048 x 8192    (33,554,432 B)
  bf16* xn   = (bf16*)(ws + 118489088);      // 4096 x 2048    (16,777,216 B)
  bf16* qb   = (bf16*)(ws + 135266304);      // 4096 x 2048    (16,777,216 B)
  bf16* kb   = (bf16*)(ws + 152043520);      // 2 x 2048 x 128 ( 1,048,576 B)
  bf16* vtb  = (bf16*)(ws + 153092096);      // 2 x 128 x 2048 ( 1,048,576 B)
  bf16* gb   = (bf16*)(ws + 154140672);      // 4096 x 8192    (67,108,864 B)
  // total 221,249,536 B

  transpose_cast_kernel<<<dim3(584, 64), dim3(32, 8), 0, stream>>>(w_fused, wfT, 2048, 18688, 1);
  transpose_cast_kernel<<<dim3(64, 64), dim3(32, 8), 0, stream>>>(w_attn, waoT, 2048, 2048, 0);
  transpose_cast_kernel<<<dim3(64, 256), dim3(32, 8), 0, stream>>>(w_ff, wffT, 8192, 2048, 0);
  ln_kernel<<<4096, 256, 0, stream>>>(x, gamma, xn);
  // fused GEMM: M=4096 N=18688 K=2048, 256x256 tiles -> grid 16*73=1168 (%8==0)
  gemm8p<0, 4><<<dim3(1168), 512, 0, stream>>>(xn, wfT, 2048, 16,
                                               qb, kb, vtb, gb, nullptr);
  rope_q_kernel<<<16384, 256, 0, stream>>>(qb);
  rope_k_kernel<<<1024, 256, 0, stream>>>(kb);
  attn_kernel<<<dim3(32, 32), 256, 0, stream>>>(qb, kb, vtb, qb, vl);
  // attn-out: M=4096 N=2048 K=2048, 256x128 tiles -> grid 16*16=256
  gemm8p<1, 2><<<dim3(256), 512, 0, stream>>>(qb, waoT, 2048, 16,
                                              nullptr, nullptr, nullptr, nullptr, out);
  // ff-out: M=4096 N=2048 K=8192, 256x128 tiles -> grid 16*16=256
  gemm8p<2, 2><<<dim3(256), 512, 0, stream>>>(gb, wffT, 8192, 16,
                                              nullptr, nullptr, nullptr, nullptr, out);
}